// Round 8
// baseline (167.919 us; speedup 1.0000x reference)
//
#include <hip/hip_runtime.h>
#include <cstdint>

#define E_CNT 131072
#define N_CNT 4096

typedef short bf16x8 __attribute__((ext_vector_type(8)));
typedef float f32x4 __attribute__((ext_vector_type(4)));

__device__ __forceinline__ ushort f2bf(float f) {
  union { float f; unsigned u; } v; v.f = f;
  unsigned r = v.u + 0x7FFFu + ((v.u >> 16) & 1u);
  return (ushort)(r >> 16);
}

// ---- combine: W1 basis-combine+transpose | root1^T  (latency-bound part) --
// [0,256):   wt1[r*64+o][i] = f2bf(sum_b att1[r,b]*basis1[b,i,o]), r<8
// [256,384): root1^T -> wt1 rows 512..575
__global__ __launch_bounds__(256) void k_combine(const float* __restrict__ att1,
                                                 const float* __restrict__ basis1,
                                                 const float* __restrict__ root1,
                                                 ushort* __restrict__ wt1) {
  __shared__ float sT[32 * 33];
  int bid = blockIdx.x, t = threadIdx.x;
  if (bid < 256) {
    int i0 = (bid >> 1) * 32, o0 = (bid & 1) * 32;
    int ol = t & 31, ir = t >> 5;      // ir = 0..7
    float a[8][4] = {};
    for (int b = 0; b < 30; b += 2) {  // unroll x2: 8 loads in flight
      float v0[4], v1[4];
#pragma unroll
      for (int k = 0; k < 4; ++k) {
        size_t ofs = (size_t)(i0 + ir + k * 8) * 64 + o0 + ol;
        v0[k] = basis1[(size_t)b * 262144 + ofs];
        v1[k] = basis1[(size_t)(b + 1) * 262144 + ofs];
      }
#pragma unroll
      for (int r = 0; r < 8; ++r) {
        float w0 = att1[r * 30 + b], w1 = att1[r * 30 + b + 1];
#pragma unroll
        for (int k = 0; k < 4; ++k) a[r][k] += w0 * v0[k] + w1 * v1[k];
      }
    }
    for (int r = 0; r < 8; ++r) {
#pragma unroll
      for (int k = 0; k < 4; ++k) sT[ol * 33 + ir + k * 8] = a[r][k];
      __syncthreads();
#pragma unroll
      for (int k = 0; k < 4; ++k) {
        int orow = ir + k * 8, icol = ol;
        wt1[(size_t)(r * 64 + o0 + orow) * 4096 + i0 + icol] = f2bf(sT[orow * 33 + icol]);
      }
      __syncthreads();
    }
  } else {
    int bb = bid - 256;                // 128 blocks: 32 i-rows each
    int i0 = bb * 32;
    int ol = t & 31, ir = t >> 5;
    for (int oh = 0; oh < 2; ++oh) {
      int o0 = oh * 32;
#pragma unroll
      for (int k = 0; k < 4; ++k)
        sT[ol * 33 + ir + k * 8] = root1[(size_t)(i0 + ir + k * 8) * 64 + o0 + ol];
      __syncthreads();
#pragma unroll
      for (int k = 0; k < 4; ++k) {
        int orow = ir + k * 8, icol = ol;
        wt1[(size_t)(512 + o0 + orow) * 4096 + i0 + icol] = f2bf(sT[orow * 33 + icol]);
      }
      __syncthreads();
    }
  }
}

// ---- cvt: x fp32->bf16 (8 floats/thread) | deg histogram -----------------
// [0,8192): cvt ; [8192,8704): deg
__global__ __launch_bounds__(256) void k_cvt(const float4* __restrict__ x,
                                             ushort* __restrict__ xbf,
                                             const int* __restrict__ dstp,
                                             int* __restrict__ deg) {
  int bid = blockIdx.x, t = threadIdx.x;
  if (bid < 8192) {
    int i = bid * 256 + t;
    float4 v0 = x[i * 2], v1 = x[i * 2 + 1];
    ushort o[8];
    o[0] = f2bf(v0.x); o[1] = f2bf(v0.y); o[2] = f2bf(v0.z); o[3] = f2bf(v0.w);
    o[4] = f2bf(v1.x); o[5] = f2bf(v1.y); o[6] = f2bf(v1.z); o[7] = f2bf(v1.w);
    *(ulonglong2*)(xbf + (size_t)i * 8) = *(const ulonglong2*)o;
  } else {
    int e = (bid - 8192) * 256 + t;
    atomicAdd(&deg[dstp[e]], 1);
  }
}

// ---------------- exclusive scan over 4096 degrees (1 block) --------------
__global__ __launch_bounds__(1024) void k_scan(const int* __restrict__ deg,
                                               int* __restrict__ rowptr,
                                               int* __restrict__ cursor,
                                               float* __restrict__ dinv) {
  __shared__ int part[1024];
  int t = threadIdx.x;
  int base = t * 4;
  int d0 = deg[base], d1 = deg[base + 1], d2 = deg[base + 2], d3 = deg[base + 3];
  int s = d0 + d1 + d2 + d3;
  part[t] = s;
  __syncthreads();
  for (int off = 1; off < 1024; off <<= 1) {
    int v = part[t];
    int u = (t >= off) ? part[t - off] : 0;
    __syncthreads();
    part[t] = v + u;
    __syncthreads();
  }
  int incl = part[t];
  int excl = incl - s;
  int p0 = excl, p1 = excl + d0, p2 = p1 + d1, p3 = p2 + d2;
  rowptr[base] = p0; rowptr[base + 1] = p1; rowptr[base + 2] = p2; rowptr[base + 3] = p3;
  cursor[base] = p0; cursor[base + 1] = p1; cursor[base + 2] = p2; cursor[base + 3] = p3;
  dinv[base]     = 1.0f / fmaxf((float)d0, 1.0f);
  dinv[base + 1] = 1.0f / fmaxf((float)d1, 1.0f);
  dinv[base + 2] = 1.0f / fmaxf((float)d2, 1.0f);
  dinv[base + 3] = 1.0f / fmaxf((float)d3, 1.0f);
  if (t == 1023) rowptr[4096] = incl;
}

// ---------------- fused mid: CSR-fill | W2 combine -------------------------
__global__ __launch_bounds__(256) void k_mid(const int* __restrict__ srcp,
                                             const int* __restrict__ dstp,
                                             const int* __restrict__ et,
                                             int* __restrict__ cursor,
                                             int* __restrict__ spack,
                                             const float* __restrict__ att2,
                                             const float* __restrict__ basis2,
                                             const float* __restrict__ root2,
                                             float* __restrict__ w2e) {
  int bid = blockIdx.x, t = threadIdx.x;
  if (bid < 512) {
    int e = bid * 256 + t;
    int d = dstp[e];
    int pos = atomicAdd(&cursor[d], 1);
    spack[pos] = (srcp[e] << 3) | et[e];
  } else {
    int r = bid - 512;  // 0..8
    for (int q = t; q < 1024; q += 256) {
      float a = 0.f;
      if (r < 8) {
        for (int b = 0; b < 30; ++b) a += att2[r * 30 + b] * basis2[b * 1024 + q];
      } else {
        a = root2[q];
      }
      w2e[r * 1024 + q] = a;
    }
  }
}

// ---------------- GEMM v3: c1[4096][576] += xbf @ wt1^T -------------------
// BM=128 BN=192 BK=64, SPLITK=8 (8 K-steps of 64), 256 thr (2Mx2N waves,
// wave tile 64x96, acc[4][6] -> 24 MFMA : 10 ds_read per wave-K-step).
// Grid 768 = 3 blocks/CU exactly. kp = bid&7 -> each XCD owns one K-chunk
// (its 590KB B panel L2-resident); 3 bn-blocks sharing an A panel are
// dispatch-adjacent on the same XCD. Staged bytes: 245MB (was 442MB).
// Chunk-XOR LDS swizzle both-sides (rule #21). Atomic f32 epilogue.
__global__ __launch_bounds__(256, 3) void k_gemm1(const ushort* __restrict__ xbf,
                                                  const ushort* __restrict__ wt1,
                                                  float* __restrict__ c1) {
  __shared__ __align__(16) ushort As[128 * 64];  // 16KB
  __shared__ __align__(16) ushort Bs[192 * 64];  // 24KB
  int bid = blockIdx.x;
  int kp = bid & 7, rem = bid >> 3;   // rem in [0,96)
  int bm = rem / 3, bn = rem % 3;
  int m0 = bm * 128, n0 = bn * 192, kbase = kp * 512;
  int tid = threadIdx.x;
  int lane = tid & 63, wid = tid >> 6;
  int wm = wid >> 1, wn = wid & 1;

  f32x4 acc[4][6] = {};

  for (int tt = 0; tt < 8; ++tt) {
    int k0 = kbase + tt * 64;
#pragma unroll
    for (int it = 0; it < 4; ++it) {
      int flat = it * 256 + tid;
      int row = flat >> 3, gg = flat & 7;
      int gcol = k0 + ((gg ^ (row & 7)) << 3);  // pre-swizzled global source
      const ushort* g = xbf + (size_t)(m0 + row) * 4096 + gcol;
      ushort* l = &As[(it * 256 + wid * 64) * 8];  // linear LDS dest
      __builtin_amdgcn_global_load_lds((const __attribute__((address_space(1))) void*)g,
                                       (__attribute__((address_space(3))) void*)l, 16, 0, 0);
    }
#pragma unroll
    for (int it = 0; it < 6; ++it) {
      int flat = it * 256 + tid;
      int row = flat >> 3, gg = flat & 7;
      int gcol = k0 + ((gg ^ (row & 7)) << 3);
      const ushort* g = wt1 + (size_t)(n0 + row) * 4096 + gcol;
      ushort* l = &Bs[(it * 256 + wid * 64) * 8];
      __builtin_amdgcn_global_load_lds((const __attribute__((address_space(1))) void*)g,
                                       (__attribute__((address_space(3))) void*)l, 16, 0, 0);
    }
    __syncthreads();  // vmcnt(0) drain: all waves' stage landed
    int q = lane >> 4, sw = lane & 7, r16 = lane & 15;
#pragma unroll
    for (int ks = 0; ks < 2; ++ks) {
      int co = ((ks * 4 + q) ^ sw) << 3;
      bf16x8 b[6], a[4];
#pragma unroll
      for (int ni = 0; ni < 6; ++ni)
        b[ni] = *(const bf16x8*)&Bs[(wn * 96 + ni * 16 + r16) * 64 + co];
#pragma unroll
      for (int mi = 0; mi < 4; ++mi)
        a[mi] = *(const bf16x8*)&As[(wm * 64 + mi * 16 + r16) * 64 + co];
      __builtin_amdgcn_s_setprio(1);
#pragma unroll
      for (int mi = 0; mi < 4; ++mi)
#pragma unroll
        for (int ni = 0; ni < 6; ++ni)
          acc[mi][ni] = __builtin_amdgcn_mfma_f32_16x16x32_bf16(a[mi], b[ni], acc[mi][ni], 0, 0, 0);
      __builtin_amdgcn_s_setprio(0);
    }
    __syncthreads();  // LDS free for next stage
  }

  int cf = lane & 15, rf4 = (lane >> 4) * 4;
#pragma unroll
  for (int mi = 0; mi < 4; ++mi)
#pragma unroll
    for (int ni = 0; ni < 6; ++ni) {
      int gcol = n0 + wn * 96 + ni * 16 + cf;
#pragma unroll
      for (int j = 0; j < 4; ++j) {
        int grow = m0 + wm * 64 + mi * 16 + rf4 + j;
        atomicAdd(&c1[(size_t)grow * 576 + gcol], acc[mi][ni][j]);
      }
    }
}

// -------- fused layer-1 aggregate + relu + layer-2 transform (4 nodes/blk) -
__global__ __launch_bounds__(256) void k_agg1h2(const float* __restrict__ c1,
                                                const int* __restrict__ rowptr,
                                                const int* __restrict__ spack,
                                                const float* __restrict__ dinv,
                                                const float* __restrict__ bias1,
                                                const float* __restrict__ w2e,
                                                float* __restrict__ h2c) {
  __shared__ float sh[4][64];
  int g = threadIdx.x >> 6, t = threadIdx.x & 63;
  int n = blockIdx.x * 4 + g;
  int s0 = rowptr[n], s1 = rowptr[n + 1];
  float acc = 0.f;
  int e = s0;
  for (; e + 3 < s1; e += 4) {
    int p0 = spack[e], p1 = spack[e + 1], p2 = spack[e + 2], p3 = spack[e + 3];
    float v0 = c1[(size_t)(p0 >> 3) * 576 + (p0 & 7) * 64 + t];
    float v1 = c1[(size_t)(p1 >> 3) * 576 + (p1 & 7) * 64 + t];
    float v2 = c1[(size_t)(p2 >> 3) * 576 + (p2 & 7) * 64 + t];
    float v3 = c1[(size_t)(p3 >> 3) * 576 + (p3 & 7) * 64 + t];
    acc += (v0 + v1) + (v2 + v3);
  }
  for (; e < s1; ++e) {
    int p = spack[e];
    acc += c1[(size_t)(p >> 3) * 576 + (p & 7) * 64 + t];
  }
  float v = acc * dinv[n] + c1[(size_t)n * 576 + 512 + t] + bias1[t];
  sh[g][t] = fmaxf(v, 0.f);
  __syncthreads();
  float* o = h2c + (size_t)n * 144;
  for (int rc = t; rc < 144; rc += 64) {
    int r9 = rc >> 4, c = rc & 15;
    const float* w = w2e + r9 * 1024 + c;
    float a = 0.f;
#pragma unroll
    for (int hh = 0; hh < 64; ++hh) a += sh[g][hh] * w[hh * 16];
    o[rc] = a;
  }
}

// ---------------- layer-2 aggregate + root + bias + log_softmax -----------
__global__ __launch_bounds__(64) void k_agg2(const float* __restrict__ h2c,
                                             const int* __restrict__ rowptr,
                                             const int* __restrict__ spack,
                                             const float* __restrict__ dinv,
                                             const float* __restrict__ bias2,
                                             float* __restrict__ out) {
  __shared__ float red[64];
  int n = blockIdx.x, t = threadIdx.x;
  int c = t & 15, q = t >> 4;
  int s0 = rowptr[n], s1 = rowptr[n + 1];
  float acc = 0.f;
  for (int e = s0 + q; e < s1; e += 4) {
    int p = spack[e];
    acc += h2c[(size_t)(p >> 3) * 144 + (p & 7) * 16 + c];
  }
  red[t] = acc;
  __syncthreads();
  if (t < 16) {
    float sum = red[c] + red[16 + c] + red[32 + c] + red[48 + c];
    float v = sum * dinv[n] + h2c[(size_t)n * 144 + 128 + c] + bias2[c];
    float m = v;
#pragma unroll
    for (int off = 1; off < 16; off <<= 1) m = fmaxf(m, __shfl_xor(m, off, 64));
    float ex = expf(v - m);
    float s = ex;
#pragma unroll
    for (int off = 1; off < 16; off <<= 1) s += __shfl_xor(s, off, 64);
    out[n * 16 + c] = v - m - logf(s);
  }
}

extern "C" void kernel_launch(void* const* d_in, const int* in_sizes, int n_in,
                              void* d_out, int out_size, void* d_ws, size_t ws_size,
                              hipStream_t stream) {
  const float* x      = (const float*)d_in[0];
  const int*   ei     = (const int*)d_in[1];
  const int*   et     = (const int*)d_in[2];
  const float* basis1 = (const float*)d_in[3];
  const float* att1   = (const float*)d_in[4];
  const float* root1  = (const float*)d_in[5];
  const float* bias1  = (const float*)d_in[6];
  const float* basis2 = (const float*)d_in[7];
  const float* att2   = (const float*)d_in[8];
  const float* root2  = (const float*)d_in[9];
  const float* bias2  = (const float*)d_in[10];
  float* out = (float*)d_out;

  char* ws = (char*)d_ws;
  size_t off = 0;
  auto alloc = [&](size_t bytes) {
    void* p = ws + off;
    off = (off + bytes + 255) & ~(size_t)255;
    return p;
  };
  ushort* xbf  = (ushort*)alloc((size_t)N_CNT * N_CNT * 2);
  ushort* wt1  = (ushort*)alloc((size_t)576 * 4096 * 2);
  float*  c1   = (float*)alloc((size_t)N_CNT * 576 * 4);
  float*  w2e  = (float*)alloc((size_t)9 * 64 * 16 * 4);
  float*  h2c  = (float*)alloc((size_t)N_CNT * 144 * 4);
  int*    deg    = (int*)alloc(4096 * 4);
  float*  dinv   = (float*)alloc(4096 * 4);
  int*    rowptr = (int*)alloc(4097 * 4);
  int*    cursor = (int*)alloc(4096 * 4);
  int*    spack  = (int*)alloc((size_t)E_CNT * 4);

  const int* srcp = ei;
  const int* dstp = ei + E_CNT;

  hipMemsetAsync(deg, 0, 4096 * 4, stream);
  hipMemsetAsync(c1, 0, (size_t)N_CNT * 576 * 4, stream);
  k_cvt<<<8704, 256, 0, stream>>>((const float4*)x, xbf, dstp, deg);
  k_combine<<<384, 256, 0, stream>>>(att1, basis1, root1, wt1);
  k_scan<<<1, 1024, 0, stream>>>(deg, rowptr, cursor, dinv);
  k_mid<<<521, 256, 0, stream>>>(srcp, dstp, et, cursor, spack,
                                 att2, basis2, root2, w2e);
  k_gemm1<<<768, 256, 0, stream>>>(xbf, wt1, c1);
  k_agg1h2<<<1024, 256, 0, stream>>>(c1, rowptr, spack, dinv, bias1, w2e, h2c);
  k_agg2<<<4096, 64, 0, stream>>>(h2c, rowptr, spack, dinv, bias2, out);
}

// Round 9
// 142.979 us; speedup vs baseline: 1.1744x; 1.1744x over previous
//
#include <hip/hip_runtime.h>
#include <cstdint>

#define E_CNT 131072
#define N_CNT 4096

typedef short bf16x8 __attribute__((ext_vector_type(8)));
typedef float f32x4 __attribute__((ext_vector_type(4)));

__device__ __forceinline__ ushort f2bf(float f) {
  union { float f; unsigned u; } v; v.f = f;
  unsigned r = v.u + 0x7FFFu + ((v.u >> 16) & 1u);
  return (ushort)(r >> 16);
}

// ---- combine: W1 -> FRAGMENTED bf16 layout | root1 frags | deg histogram --
// wt1f frag (nt,kt): 64 lanes x 16B; lane l = W[nt*16+(l&15)][kt*32+(l>>4)*8 ..+8]
// [0,256):   basis combine: block = (i-tile 32 = kt) x (o-half 32)
// [256,384): root1 -> nt 32..35
// [384,896): degree histogram
__global__ __launch_bounds__(256) void k_combine(const float* __restrict__ att1,
                                                 const float* __restrict__ basis1,
                                                 const float* __restrict__ root1,
                                                 ushort* __restrict__ wt1f,
                                                 const int* __restrict__ dstp,
                                                 int* __restrict__ deg) {
  __shared__ float sT[32 * 33];
  int bid = blockIdx.x, t = threadIdx.x;
  if (bid < 256) {
    int i0 = (bid >> 1) * 32, o0 = (bid & 1) * 32;
    int kt = i0 >> 5;
    int ol = t & 31, ir = t >> 5;      // ir = 0..7
    float a[8][4] = {};
    for (int b = 0; b < 30; b += 2) {
      float v0[4], v1[4];
#pragma unroll
      for (int k = 0; k < 4; ++k) {
        size_t ofs = (size_t)(i0 + ir + k * 8) * 64 + o0 + ol;
        v0[k] = basis1[(size_t)b * 262144 + ofs];
        v1[k] = basis1[(size_t)(b + 1) * 262144 + ofs];
      }
#pragma unroll
      for (int r = 0; r < 8; ++r) {
        float w0 = att1[r * 30 + b], w1 = att1[r * 30 + b + 1];
#pragma unroll
        for (int k = 0; k < 4; ++k) a[r][k] += w0 * v0[k] + w1 * v1[k];
      }
    }
    for (int r = 0; r < 8; ++r) {
      // sT[o_local][i_local], stride 33
#pragma unroll
      for (int k = 0; k < 4; ++k) sT[ol * 33 + ir + k * 8] = a[r][k];
      __syncthreads();
      if (t < 128) {
        int l = t & 63, f = t >> 6;
        int o_local = f * 16 + (l & 15);
        int i_local = (l >> 4) * 8;
        const float* sp = &sT[o_local * 33 + i_local];
        ushort o8[8];
#pragma unroll
        for (int j = 0; j < 8; ++j) o8[j] = f2bf(sp[j]);
        int nt = r * 4 + (o0 >> 4) + f;
        ushort* dst = wt1f + ((size_t)(nt * 128 + kt) * 64 + l) * 8;
        *(ulonglong2*)dst = *(const ulonglong2*)o8;
      }
      __syncthreads();
    }
  } else if (bid < 384) {
    int bb = bid - 256;                // kt = bb, 32 i-rows
    int i0 = bb * 32, kt = bb;
    int ol = t & 31, ir = t >> 5;
    for (int oh = 0; oh < 2; ++oh) {
      int o0 = oh * 32;
#pragma unroll
      for (int k = 0; k < 4; ++k)
        sT[ol * 33 + ir + k * 8] = root1[(size_t)(i0 + ir + k * 8) * 64 + o0 + ol];
      __syncthreads();
      if (t < 128) {
        int l = t & 63, f = t >> 6;
        int o_local = f * 16 + (l & 15);
        int i_local = (l >> 4) * 8;
        const float* sp = &sT[o_local * 33 + i_local];
        ushort o8[8];
#pragma unroll
        for (int j = 0; j < 8; ++j) o8[j] = f2bf(sp[j]);
        int nt = 32 + oh * 2 + f;
        ushort* dst = wt1f + ((size_t)(nt * 128 + kt) * 64 + l) * 8;
        *(ulonglong2*)dst = *(const ulonglong2*)o8;
      }
      __syncthreads();
    }
  } else {
    int e = (bid - 384) * 256 + t;
    atomicAdd(&deg[dstp[e]], 1);
  }
}

// ---------------- exclusive scan over 4096 degrees (1 block) --------------
__global__ __launch_bounds__(1024) void k_scan(const int* __restrict__ deg,
                                               int* __restrict__ rowptr,
                                               int* __restrict__ cursor,
                                               float* __restrict__ dinv) {
  __shared__ int part[1024];
  int t = threadIdx.x;
  int base = t * 4;
  int d0 = deg[base], d1 = deg[base + 1], d2 = deg[base + 2], d3 = deg[base + 3];
  int s = d0 + d1 + d2 + d3;
  part[t] = s;
  __syncthreads();
  for (int off = 1; off < 1024; off <<= 1) {
    int v = part[t];
    int u = (t >= off) ? part[t - off] : 0;
    __syncthreads();
    part[t] = v + u;
    __syncthreads();
  }
  int incl = part[t];
  int excl = incl - s;
  int p0 = excl, p1 = excl + d0, p2 = p1 + d1, p3 = p2 + d2;
  rowptr[base] = p0; rowptr[base + 1] = p1; rowptr[base + 2] = p2; rowptr[base + 3] = p3;
  cursor[base] = p0; cursor[base + 1] = p1; cursor[base + 2] = p2; cursor[base + 3] = p3;
  dinv[base]     = 1.0f / fmaxf((float)d0, 1.0f);
  dinv[base + 1] = 1.0f / fmaxf((float)d1, 1.0f);
  dinv[base + 2] = 1.0f / fmaxf((float)d2, 1.0f);
  dinv[base + 3] = 1.0f / fmaxf((float)d3, 1.0f);
  if (t == 1023) rowptr[4096] = incl;
}

// ---------------- fused mid: CSR-fill | W2 combine -------------------------
__global__ __launch_bounds__(256) void k_mid(const int* __restrict__ srcp,
                                             const int* __restrict__ dstp,
                                             const int* __restrict__ et,
                                             int* __restrict__ cursor,
                                             int* __restrict__ spack,
                                             const float* __restrict__ att2,
                                             const float* __restrict__ basis2,
                                             const float* __restrict__ root2,
                                             float* __restrict__ w2e) {
  int bid = blockIdx.x, t = threadIdx.x;
  if (bid < 512) {
    int e = bid * 256 + t;
    int d = dstp[e];
    int pos = atomicAdd(&cursor[d], 1);
    spack[pos] = (srcp[e] << 3) | et[e];
  } else {
    int r = bid - 512;  // 0..8
    for (int q = t; q < 1024; q += 256) {
      float a = 0.f;
      if (r < 8) {
        for (int b = 0; b < 30; ++b) a += att2[r * 30 + b] * basis2[b * 1024 + q];
      } else {
        a = root2[q];
      }
      w2e[r * 1024 + q] = a;
    }
  }
}

// ---------------- GEMM v4: c1[4096][576] += x(f32) @ W^T ------------------
// BM=128 BN=288 BK=32, SPLITK=4, grid 256 (1 block/CU). 256 thr, 4 waves
// 2Mx2N, wave tile 64x144, acc[4][9] -> 36 MFMA : 4 ds_read : 9 L2-frag
// loads per step. A: x fp32 -> reg cvt -> 8KB LDS (dbuf, chunk-XOR swizzle
// both sides). B: PRE-FRAGMENTED wt1f, one coalesced 1KB dwordx4 per frag,
// L2-resident (kp pinned per XCD pair). Atomic f32 epilogue (9.4M).
__global__ __launch_bounds__(256, 2) void k_gemm1(const float* __restrict__ x,
                                                  const ushort* __restrict__ wt1f,
                                                  float* __restrict__ c1) {
  __shared__ __align__(16) ushort As[2][128 * 32];  // 16KB total
  int bid = blockIdx.x;
  int xcd = bid & 7;
  int kp = xcd >> 1, p = xcd & 1;
  int combo = p * 32 + (bid >> 3);   // 0..63
  int bn = combo & 1, bm = combo >> 1;
  int m0 = bm * 128, n0 = bn * 288, kbase = kp * 1024;
  int tid = threadIdx.x, lane = tid & 63, wid = tid >> 6;
  int wm = wid >> 1, wn = wid & 1;
  int r16 = lane & 15, q = lane >> 4;

  // A staging: thread -> row tid>>1 (0..127), k-half tid&1 (16 fp32 = 64B)
  int arow = tid >> 1, ah = tid & 1;
  const float* axp = x + (size_t)(m0 + arow) * 4096 + kbase + ah * 16;
  int wofs0 = arow * 32 + ((((ah << 1) | 0) ^ (arow & 3)) << 3);
  int wofs1 = arow * 32 + ((((ah << 1) | 1) ^ (arow & 3)) << 3);

  int ntbase = bn * 18 + wn * 9;
  int ktbase = kp * 32;

  f32x4 acc[4][9] = {};

  // prologue: stage buf0
  {
    float4 v0 = *(const float4*)(axp + 0);
    float4 v1 = *(const float4*)(axp + 4);
    float4 v2 = *(const float4*)(axp + 8);
    float4 v3 = *(const float4*)(axp + 12);
    ushort o0[8] = {f2bf(v0.x), f2bf(v0.y), f2bf(v0.z), f2bf(v0.w),
                    f2bf(v1.x), f2bf(v1.y), f2bf(v1.z), f2bf(v1.w)};
    ushort o1[8] = {f2bf(v2.x), f2bf(v2.y), f2bf(v2.z), f2bf(v2.w),
                    f2bf(v3.x), f2bf(v3.y), f2bf(v3.z), f2bf(v3.w)};
    *(ulonglong2*)&As[0][wofs0] = *(const ulonglong2*)o0;
    *(ulonglong2*)&As[0][wofs1] = *(const ulonglong2*)o1;
  }
  __syncthreads();

  for (int t = 0; t < 32; ++t) {
    int cur = t & 1;
    // prefetch next A slice into regs (overlaps this step's compute)
    float4 n0v, n1v, n2v, n3v;
    if (t + 1 < 32) {
      const float* np = axp + (t + 1) * 32;
      n0v = *(const float4*)(np + 0);
      n1v = *(const float4*)(np + 4);
      n2v = *(const float4*)(np + 8);
      n3v = *(const float4*)(np + 12);
    }
    // B fragments: one coalesced 16B/lane load each, L2-resident
    int kt = ktbase + t;
    bf16x8 bf[9];
#pragma unroll
    for (int ni = 0; ni < 9; ++ni)
      bf[ni] = *(const bf16x8*)(wt1f + ((size_t)((ntbase + ni) * 128 + kt) * 64 + lane) * 8);
    // A fragments from LDS (swizzled)
    bf16x8 af[4];
#pragma unroll
    for (int mi = 0; mi < 4; ++mi) {
      int row = wm * 64 + mi * 16 + r16;
      af[mi] = *(const bf16x8*)&As[cur][row * 32 + ((q ^ (row & 3)) << 3)];
    }
    __builtin_amdgcn_s_setprio(1);
#pragma unroll
    for (int mi = 0; mi < 4; ++mi)
#pragma unroll
      for (int ni = 0; ni < 9; ++ni)
        acc[mi][ni] = __builtin_amdgcn_mfma_f32_16x16x32_bf16(af[mi], bf[ni], acc[mi][ni], 0, 0, 0);
    __builtin_amdgcn_s_setprio(0);
    // write prefetched A into other buffer
    if (t + 1 < 32) {
      ushort o0[8] = {f2bf(n0v.x), f2bf(n0v.y), f2bf(n0v.z), f2bf(n0v.w),
                      f2bf(n1v.x), f2bf(n1v.y), f2bf(n1v.z), f2bf(n1v.w)};
      ushort o1[8] = {f2bf(n2v.x), f2bf(n2v.y), f2bf(n2v.z), f2bf(n2v.w),
                      f2bf(n3v.x), f2bf(n3v.y), f2bf(n3v.z), f2bf(n3v.w)};
      *(ulonglong2*)&As[cur ^ 1][wofs0] = *(const ulonglong2*)o0;
      *(ulonglong2*)&As[cur ^ 1][wofs1] = *(const ulonglong2*)o1;
    }
    __syncthreads();
  }

  int rf4 = q * 4;
#pragma unroll
  for (int mi = 0; mi < 4; ++mi)
#pragma unroll
    for (int ni = 0; ni < 9; ++ni) {
      int gcol = n0 + wn * 144 + ni * 16 + r16;
#pragma unroll
      for (int j = 0; j < 4; ++j) {
        int grow = m0 + wm * 64 + mi * 16 + rf4 + j;
        atomicAdd(&c1[(size_t)grow * 576 + gcol], acc[mi][ni][j]);
      }
    }
}

// -------- fused layer-1 aggregate + relu + layer-2 transform (4 nodes/blk) -
__global__ __launch_bounds__(256) void k_agg1h2(const float* __restrict__ c1,
                                                const int* __restrict__ rowptr,
                                                const int* __restrict__ spack,
                                                const float* __restrict__ dinv,
                                                const float* __restrict__ bias1,
                                                const float* __restrict__ w2e,
                                                float* __restrict__ h2c) {
  __shared__ float sh[4][64];
  int g = threadIdx.x >> 6, t = threadIdx.x & 63;
  int n = blockIdx.x * 4 + g;
  int s0 = rowptr[n], s1 = rowptr[n + 1];
  float acc = 0.f;
  int e = s0;
  for (; e + 3 < s1; e += 4) {
    int p0 = spack[e], p1 = spack[e + 1], p2 = spack[e + 2], p3 = spack[e + 3];
    float v0 = c1[(size_t)(p0 >> 3) * 576 + (p0 & 7) * 64 + t];
    float v1 = c1[(size_t)(p1 >> 3) * 576 + (p1 & 7) * 64 + t];
    float v2 = c1[(size_t)(p2 >> 3) * 576 + (p2 & 7) * 64 + t];
    float v3 = c1[(size_t)(p3 >> 3) * 576 + (p3 & 7) * 64 + t];
    acc += (v0 + v1) + (v2 + v3);
  }
  for (; e < s1; ++e) {
    int p = spack[e];
    acc += c1[(size_t)(p >> 3) * 576 + (p & 7) * 64 + t];
  }
  float v = acc * dinv[n] + c1[(size_t)n * 576 + 512 + t] + bias1[t];
  sh[g][t] = fmaxf(v, 0.f);
  __syncthreads();
  float* o = h2c + (size_t)n * 144;
  for (int rc = t; rc < 144; rc += 64) {
    int r9 = rc >> 4, c = rc & 15;
    const float* w = w2e + r9 * 1024 + c;
    float a = 0.f;
#pragma unroll
    for (int hh = 0; hh < 64; ++hh) a += sh[g][hh] * w[hh * 16];
    o[rc] = a;
  }
}

// ---------------- layer-2 aggregate + root + bias + log_softmax -----------
__global__ __launch_bounds__(64) void k_agg2(const float* __restrict__ h2c,
                                             const int* __restrict__ rowptr,
                                             const int* __restrict__ spack,
                                             const float* __restrict__ dinv,
                                             const float* __restrict__ bias2,
                                             float* __restrict__ out) {
  __shared__ float red[64];
  int n = blockIdx.x, t = threadIdx.x;
  int c = t & 15, q = t >> 4;
  int s0 = rowptr[n], s1 = rowptr[n + 1];
  float acc = 0.f;
  for (int e = s0 + q; e < s1; e += 4) {
    int p = spack[e];
    acc += h2c[(size_t)(p >> 3) * 144 + (p & 7) * 16 + c];
  }
  red[t] = acc;
  __syncthreads();
  if (t < 16) {
    float sum = red[c] + red[16 + c] + red[32 + c] + red[48 + c];
    float v = sum * dinv[n] + h2c[(size_t)n * 144 + 128 + c] + bias2[c];
    float m = v;
#pragma unroll
    for (int off = 1; off < 16; off <<= 1) m = fmaxf(m, __shfl_xor(m, off, 64));
    float ex = expf(v - m);
    float s = ex;
#pragma unroll
    for (int off = 1; off < 16; off <<= 1) s += __shfl_xor(s, off, 64);
    out[n * 16 + c] = v - m - logf(s);
  }
}

extern "C" void kernel_launch(void* const* d_in, const int* in_sizes, int n_in,
                              void* d_out, int out_size, void* d_ws, size_t ws_size,
                              hipStream_t stream) {
  const float* x      = (const float*)d_in[0];
  const int*   ei     = (const int*)d_in[1];
  const int*   et     = (const int*)d_in[2];
  const float* basis1 = (const float*)d_in[3];
  const float* att1   = (const float*)d_in[4];
  const float* root1  = (const float*)d_in[5];
  const float* bias1  = (const float*)d_in[6];
  const float* basis2 = (const float*)d_in[7];
  const float* att2   = (const float*)d_in[8];
  const float* root2  = (const float*)d_in[9];
  const float* bias2  = (const float*)d_in[10];
  float* out = (float*)d_out;

  char* ws = (char*)d_ws;
  size_t off = 0;
  auto alloc = [&](size_t bytes) {
    void* p = ws + off;
    off = (off + bytes + 255) & ~(size_t)255;
    return p;
  };
  ushort* wt1f = (ushort*)alloc((size_t)36 * 128 * 64 * 8 * 2);  // 4.7MB frags
  float*  c1   = (float*)alloc((size_t)N_CNT * 576 * 4);
  float*  w2e  = (float*)alloc((size_t)9 * 64 * 16 * 4);
  float*  h2c  = (float*)alloc((size_t)N_CNT * 144 * 4);
  int*    deg    = (int*)alloc(4096 * 4);
  float*  dinv   = (float*)alloc(4096 * 4);
  int*    rowptr = (int*)alloc(4097 * 4);
  int*    cursor = (int*)alloc(4096 * 4);
  int*    spack  = (int*)alloc((size_t)E_CNT * 4);

  const int* srcp = ei;
  const int* dstp = ei + E_CNT;

  hipMemsetAsync(deg, 0, 4096 * 4, stream);
  hipMemsetAsync(c1, 0, (size_t)N_CNT * 576 * 4, stream);
  k_combine<<<896, 256, 0, stream>>>(att1, basis1, root1, wt1f, dstp, deg);
  k_scan<<<1, 1024, 0, stream>>>(deg, rowptr, cursor, dinv);
  k_mid<<<521, 256, 0, stream>>>(srcp, dstp, et, cursor, spack,
                                 att2, basis2, root2, w2e);
  k_gemm1<<<256, 256, 0, stream>>>(x, wt1f, c1);
  k_agg1h2<<<1024, 256, 0, stream>>>(c1, rowptr, spack, dinv, bias1, w2e, h2c);
  k_agg2<<<4096, 64, 0, stream>>>(h2c, rowptr, spack, dinv, bias2, out);
}

// Round 10
// 139.693 us; speedup vs baseline: 1.2021x; 1.0235x over previous
//
#include <hip/hip_runtime.h>
#include <cstdint>

#define E_CNT 131072
#define N_CNT 4096

typedef short bf16x8 __attribute__((ext_vector_type(8)));
typedef float f32x4 __attribute__((ext_vector_type(4)));

__device__ __forceinline__ ushort f2bf(float f) {
  union { float f; unsigned u; } v; v.f = f;
  unsigned r = v.u + 0x7FFFu + ((v.u >> 16) & 1u);
  return (ushort)(r >> 16);
}

// ---- combine: W1 basis-combine+transpose | root1^T | deg histogram -------
// [0,256):   wt1[r*64+o][i] = f2bf(sum_b att1[r,b]*basis1[b,i,o]), r<8
// [256,384): root1^T -> wt1 rows 512..575
// [384,896): degree histogram
__global__ __launch_bounds__(256) void k_combine(const float* __restrict__ att1,
                                                 const float* __restrict__ basis1,
                                                 const float* __restrict__ root1,
                                                 ushort* __restrict__ wt1,
                                                 const int* __restrict__ dstp,
                                                 int* __restrict__ deg) {
  __shared__ float sT[32 * 33];
  int bid = blockIdx.x, t = threadIdx.x;
  if (bid < 256) {
    int i0 = (bid >> 1) * 32, o0 = (bid & 1) * 32;
    int ol = t & 31, ir = t >> 5;      // ir = 0..7
    float a[8][4] = {};
    for (int b = 0; b < 30; b += 2) {  // unroll x2: 8 loads in flight
      float v0[4], v1[4];
#pragma unroll
      for (int k = 0; k < 4; ++k) {
        size_t ofs = (size_t)(i0 + ir + k * 8) * 64 + o0 + ol;
        v0[k] = basis1[(size_t)b * 262144 + ofs];
        v1[k] = basis1[(size_t)(b + 1) * 262144 + ofs];
      }
#pragma unroll
      for (int r = 0; r < 8; ++r) {
        float w0 = att1[r * 30 + b], w1 = att1[r * 30 + b + 1];
#pragma unroll
        for (int k = 0; k < 4; ++k) a[r][k] += w0 * v0[k] + w1 * v1[k];
      }
    }
    for (int r = 0; r < 8; ++r) {
#pragma unroll
      for (int k = 0; k < 4; ++k) sT[ol * 33 + ir + k * 8] = a[r][k];
      __syncthreads();
#pragma unroll
      for (int k = 0; k < 4; ++k) {
        int orow = ir + k * 8, icol = ol;
        wt1[(size_t)(r * 64 + o0 + orow) * 4096 + i0 + icol] = f2bf(sT[orow * 33 + icol]);
      }
      __syncthreads();
    }
  } else if (bid < 384) {
    int bb = bid - 256;                // 128 blocks: 32 i-rows each
    int i0 = bb * 32;
    int ol = t & 31, ir = t >> 5;
    for (int oh = 0; oh < 2; ++oh) {
      int o0 = oh * 32;
#pragma unroll
      for (int k = 0; k < 4; ++k)
        sT[ol * 33 + ir + k * 8] = root1[(size_t)(i0 + ir + k * 8) * 64 + o0 + ol];
      __syncthreads();
#pragma unroll
      for (int k = 0; k < 4; ++k) {
        int orow = ir + k * 8, icol = ol;
        wt1[(size_t)(512 + o0 + orow) * 4096 + i0 + icol] = f2bf(sT[orow * 33 + icol]);
      }
      __syncthreads();
    }
  } else {
    int e = (bid - 384) * 256 + t;
    atomicAdd(&deg[dstp[e]], 1);
  }
}

// ---------------- exclusive scan over 4096 degrees (1 block) --------------
__global__ __launch_bounds__(1024) void k_scan(const int* __restrict__ deg,
                                               int* __restrict__ rowptr,
                                               int* __restrict__ cursor,
                                               float* __restrict__ dinv) {
  __shared__ int part[1024];
  int t = threadIdx.x;
  int base = t * 4;
  int d0 = deg[base], d1 = deg[base + 1], d2 = deg[base + 2], d3 = deg[base + 3];
  int s = d0 + d1 + d2 + d3;
  part[t] = s;
  __syncthreads();
  for (int off = 1; off < 1024; off <<= 1) {
    int v = part[t];
    int u = (t >= off) ? part[t - off] : 0;
    __syncthreads();
    part[t] = v + u;
    __syncthreads();
  }
  int incl = part[t];
  int excl = incl - s;
  int p0 = excl, p1 = excl + d0, p2 = p1 + d1, p3 = p2 + d2;
  rowptr[base] = p0; rowptr[base + 1] = p1; rowptr[base + 2] = p2; rowptr[base + 3] = p3;
  cursor[base] = p0; cursor[base + 1] = p1; cursor[base + 2] = p2; cursor[base + 3] = p3;
  dinv[base]     = 1.0f / fmaxf((float)d0, 1.0f);
  dinv[base + 1] = 1.0f / fmaxf((float)d1, 1.0f);
  dinv[base + 2] = 1.0f / fmaxf((float)d2, 1.0f);
  dinv[base + 3] = 1.0f / fmaxf((float)d3, 1.0f);
  if (t == 1023) rowptr[4096] = incl;
}

// ---------------- fused mid: CSR-fill | W2 combine -------------------------
__global__ __launch_bounds__(256) void k_mid(const int* __restrict__ srcp,
                                             const int* __restrict__ dstp,
                                             const int* __restrict__ et,
                                             int* __restrict__ cursor,
                                             int* __restrict__ spack,
                                             const float* __restrict__ att2,
                                             const float* __restrict__ basis2,
                                             const float* __restrict__ root2,
                                             float* __restrict__ w2e) {
  int bid = blockIdx.x, t = threadIdx.x;
  if (bid < 512) {
    int e = bid * 256 + t;
    int d = dstp[e];
    int pos = atomicAdd(&cursor[d], 1);
    spack[pos] = (srcp[e] << 3) | et[e];
  } else {
    int r = bid - 512;  // 0..8
    for (int q = t; q < 1024; q += 256) {
      float a = 0.f;
      if (r < 8) {
        for (int b = 0; b < 30; ++b) a += att2[r * 30 + b] * basis2[b * 1024 + q];
      } else {
        a = root2[q];
      }
      w2e[r * 1024 + q] = a;
    }
  }
}

// ---------------- GEMM v5: c1[4096][576] += x(f32) @ wt1^T ----------------
// R5's proven skeleton (48.4us): BM=128 BN=64 BK=64, SPLITK=4, grid 1152,
// single-buffer 24KB LDS, 2-barrier loop, 4 waves 2x2 (wave 64x32), atomics.
// CHANGES vs R5: (1) A staged from x fp32 with in-register cvt (reg-staged
// ds_write_b128 into the SAME swizzled layout R5's reads use; ds_write is
// 16B/lane contiguous -> conflict-free). Kills the separate cvt kernel and
// its ~130MB of traffic. (2) XCD panel-sharing map: the 9 bn-blocks sharing
// one (bm,kp) A-panel are consecutive on one XCD (A panel L2-shared).
__global__ __launch_bounds__(256, 5) void k_gemm1(const float* __restrict__ x,
                                                  const ushort* __restrict__ wt1,
                                                  float* __restrict__ c1) {
  __shared__ __align__(16) ushort As[128 * 64];
  __shared__ __align__(16) ushort Bs[64 * 64];
  int bid = blockIdx.x;
  int xcd = bid & 7, idx = bid >> 3;        // idx 0..143 within XCD
  int bn = idx % 9, mk = idx / 9;           // bn fastest: 9 panel-sharers adjacent
  int kp = xcd >> 1, bm = ((xcd & 1) << 4) + mk;
  int m0 = bm * 128, n0 = bn * 64, kbase = kp * 1024;
  int tid = threadIdx.x;
  int lane = tid & 63, wid = tid >> 6;
  int wm = wid >> 1, wn = wid & 1;

  f32x4 acc[4][2] = {};

  for (int tt = 0; tt < 16; ++tt) {
    int k0 = kbase + tt * 64;
    // A: load f32 (pre-swizzled source chunk), cvt in reg
    float4 va[4][2];
#pragma unroll
    for (int it = 0; it < 4; ++it) {
      int flat = it * 256 + tid;
      int row = flat >> 3, gg = flat & 7;
      const float* src = x + (size_t)(m0 + row) * 4096 + k0 + ((gg ^ (row & 7)) << 3);
      va[it][0] = *(const float4*)src;
      va[it][1] = *(const float4*)(src + 4);
    }
    // B: async global->LDS (bf16, pre-swizzled source)
#pragma unroll
    for (int it = 0; it < 2; ++it) {
      int flat = it * 256 + tid;
      int row = flat >> 3, gg = flat & 7;
      int gcol = k0 + ((gg ^ (row & 7)) << 3);
      const ushort* g = wt1 + (size_t)(n0 + row) * 4096 + gcol;
      ushort* l = &Bs[(it * 256 + wid * 64) * 8];
      __builtin_amdgcn_global_load_lds((const __attribute__((address_space(1))) void*)g,
                                       (__attribute__((address_space(3))) void*)l, 16, 0, 0);
    }
    // A: cvt + ds_write_b128 (16B/lane contiguous -> conflict-free)
#pragma unroll
    for (int it = 0; it < 4; ++it) {
      int flat = it * 256 + tid;
      float4 v0 = va[it][0], v1 = va[it][1];
      ushort o8[8] = {f2bf(v0.x), f2bf(v0.y), f2bf(v0.z), f2bf(v0.w),
                      f2bf(v1.x), f2bf(v1.y), f2bf(v1.z), f2bf(v1.w)};
      *(ulonglong2*)&As[flat * 8] = *(const ulonglong2*)o8;
    }
    __syncthreads();  // drains lgkm (A writes) + vmcnt (B gload_lds)
    int q = lane >> 4, sw = lane & 7, r16 = lane & 15;
#pragma unroll
    for (int ks = 0; ks < 2; ++ks) {
      int co = ((ks * 4 + q) ^ sw) << 3;
      bf16x8 b0 = *(const bf16x8*)&Bs[(wn * 32 + 0 * 16 + r16) * 64 + co];
      bf16x8 b1 = *(const bf16x8*)&Bs[(wn * 32 + 1 * 16 + r16) * 64 + co];
      bf16x8 a0 = *(const bf16x8*)&As[(wm * 64 + 0 * 16 + r16) * 64 + co];
      bf16x8 a1 = *(const bf16x8*)&As[(wm * 64 + 1 * 16 + r16) * 64 + co];
      bf16x8 a2 = *(const bf16x8*)&As[(wm * 64 + 2 * 16 + r16) * 64 + co];
      bf16x8 a3 = *(const bf16x8*)&As[(wm * 64 + 3 * 16 + r16) * 64 + co];
      __builtin_amdgcn_s_setprio(1);
      acc[0][0] = __builtin_amdgcn_mfma_f32_16x16x32_bf16(a0, b0, acc[0][0], 0, 0, 0);
      acc[0][1] = __builtin_amdgcn_mfma_f32_16x16x32_bf16(a0, b1, acc[0][1], 0, 0, 0);
      acc[1][0] = __builtin_amdgcn_mfma_f32_16x16x32_bf16(a1, b0, acc[1][0], 0, 0, 0);
      acc[1][1] = __builtin_amdgcn_mfma_f32_16x16x32_bf16(a1, b1, acc[1][1], 0, 0, 0);
      acc[2][0] = __builtin_amdgcn_mfma_f32_16x16x32_bf16(a2, b0, acc[2][0], 0, 0, 0);
      acc[2][1] = __builtin_amdgcn_mfma_f32_16x16x32_bf16(a2, b1, acc[2][1], 0, 0, 0);
      acc[3][0] = __builtin_amdgcn_mfma_f32_16x16x32_bf16(a3, b0, acc[3][0], 0, 0, 0);
      acc[3][1] = __builtin_amdgcn_mfma_f32_16x16x32_bf16(a3, b1, acc[3][1], 0, 0, 0);
      __builtin_amdgcn_s_setprio(0);
    }
    __syncthreads();  // LDS free for next stage
  }

  int cf = lane & 15, rf4 = (lane >> 4) * 4;
#pragma unroll
  for (int mi = 0; mi < 4; ++mi)
#pragma unroll
    for (int ni = 0; ni < 2; ++ni) {
      int gcol = n0 + wn * 32 + ni * 16 + cf;
#pragma unroll
      for (int j = 0; j < 4; ++j) {
        int grow = m0 + wm * 64 + mi * 16 + rf4 + j;
        atomicAdd(&c1[(size_t)grow * 576 + gcol], acc[mi][ni][j]);
      }
    }
}

// -------- fused layer-1 aggregate + relu + layer-2 transform (4 nodes/blk) -
__global__ __launch_bounds__(256) void k_agg1h2(const float* __restrict__ c1,
                                                const int* __restrict__ rowptr,
                                                const int* __restrict__ spack,
                                                const float* __restrict__ dinv,
                                                const float* __restrict__ bias1,
                                                const float* __restrict__ w2e,
                                                float* __restrict__ h2c) {
  __shared__ float sh[4][64];
  int g = threadIdx.x >> 6, t = threadIdx.x & 63;
  int n = blockIdx.x * 4 + g;
  int s0 = rowptr[n], s1 = rowptr[n + 1];
  float acc = 0.f;
  int e = s0;
  for (; e + 3 < s1; e += 4) {
    int p0 = spack[e], p1 = spack[e + 1], p2 = spack[e + 2], p3 = spack[e + 3];
    float v0 = c1[(size_t)(p0 >> 3) * 576 + (p0 & 7) * 64 + t];
    float v1 = c1[(size_t)(p1 >> 3) * 576 + (p1 & 7) * 64 + t];
    float v2 = c1[(size_t)(p2 >> 3) * 576 + (p2 & 7) * 64 + t];
    float v3 = c1[(size_t)(p3 >> 3) * 576 + (p3 & 7) * 64 + t];
    acc += (v0 + v1) + (v2 + v3);
  }
  for (; e < s1; ++e) {
    int p = spack[e];
    acc += c1[(size_t)(p >> 3) * 576 + (p & 7) * 64 + t];
  }
  float v = acc * dinv[n] + c1[(size_t)n * 576 + 512 + t] + bias1[t];
  sh[g][t] = fmaxf(v, 0.f);
  __syncthreads();
  float* o = h2c + (size_t)n * 144;
  for (int rc = t; rc < 144; rc += 64) {
    int r9 = rc >> 4, c = rc & 15;
    const float* w = w2e + r9 * 1024 + c;
    float a = 0.f;
#pragma unroll
    for (int hh = 0; hh < 64; ++hh) a += sh[g][hh] * w[hh * 16];
    o[rc] = a;
  }
}

// ---------------- layer-2 aggregate + root + bias + log_softmax -----------
__global__ __launch_bounds__(64) void k_agg2(const float* __restrict__ h2c,
                                             const int* __restrict__ rowptr,
                                             const int* __restrict__ spack,
                                             const float* __restrict__ dinv,
                                             const float* __restrict__ bias2,
                                             float* __restrict__ out) {
  __shared__ float red[64];
  int n = blockIdx.x, t = threadIdx.x;
  int c = t & 15, q = t >> 4;
  int s0 = rowptr[n], s1 = rowptr[n + 1];
  float acc = 0.f;
  for (int e = s0 + q; e < s1; e += 4) {
    int p = spack[e];
    acc += h2c[(size_t)(p >> 3) * 144 + (p & 7) * 16 + c];
  }
  red[t] = acc;
  __syncthreads();
  if (t < 16) {
    float sum = red[c] + red[16 + c] + red[32 + c] + red[48 + c];
    float v = sum * dinv[n] + h2c[(size_t)n * 144 + 128 + c] + bias2[c];
    float m = v;
#pragma unroll
    for (int off = 1; off < 16; off <<= 1) m = fmaxf(m, __shfl_xor(m, off, 64));
    float ex = expf(v - m);
    float s = ex;
#pragma unroll
    for (int off = 1; off < 16; off <<= 1) s += __shfl_xor(s, off, 64);
    out[n * 16 + c] = v - m - logf(s);
  }
}

extern "C" void kernel_launch(void* const* d_in, const int* in_sizes, int n_in,
                              void* d_out, int out_size, void* d_ws, size_t ws_size,
                              hipStream_t stream) {
  const float* x      = (const float*)d_in[0];
  const int*   ei     = (const int*)d_in[1];
  const int*   et     = (const int*)d_in[2];
  const float* basis1 = (const float*)d_in[3];
  const float* att1   = (const float*)d_in[4];
  const float* root1  = (const float*)d_in[5];
  const float* bias1  = (const float*)d_in[6];
  const float* basis2 = (const float*)d_in[7];
  const float* att2   = (const float*)d_in[8];
  const float* root2  = (const float*)d_in[9];
  const float* bias2  = (const float*)d_in[10];
  float* out = (float*)d_out;

  char* ws = (char*)d_ws;
  size_t off = 0;
  auto alloc = [&](size_t bytes) {
    void* p = ws + off;
    off = (off + bytes + 255) & ~(size_t)255;
    return p;
  };
  ushort* wt1  = (ushort*)alloc((size_t)576 * 4096 * 2);
  float*  c1   = (float*)alloc((size_t)N_CNT * 576 * 4);
  float*  w2e  = (float*)alloc((size_t)9 * 64 * 16 * 4);
  float*  h2c  = (float*)alloc((size_t)N_CNT * 144 * 4);
  int*    deg    = (int*)alloc(4096 * 4);
  float*  dinv   = (float*)alloc(4096 * 4);
  int*    rowptr = (int*)alloc(4097 * 4);
  int*    cursor = (int*)alloc(4096 * 4);
  int*    spack  = (int*)alloc((size_t)E_CNT * 4);

  const int* srcp = ei;
  const int* dstp = ei + E_CNT;

  hipMemsetAsync(deg, 0, 4096 * 4, stream);
  hipMemsetAsync(c1, 0, (size_t)N_CNT * 576 * 4, stream);
  k_combine<<<896, 256, 0, stream>>>(att1, basis1, root1, wt1, dstp, deg);
  k_scan<<<1, 1024, 0, stream>>>(deg, rowptr, cursor, dinv);
  k_mid<<<521, 256, 0, stream>>>(srcp, dstp, et, cursor, spack,
                                 att2, basis2, root2, w2e);
  k_gemm1<<<1152, 256, 0, stream>>>(x, wt1, c1);
  k_agg1h2<<<1024, 256, 0, stream>>>(c1, rowptr, spack, dinv, bias1, w2e, h2c);
  k_agg2<<<4096, 64, 0, stream>>>(h2c, rowptr, spack, dinv, bias2, out);
}

// Round 12
// 136.207 us; speedup vs baseline: 1.2328x; 1.0256x over previous
//
#include <hip/hip_runtime.h>
#include <cstdint>

#define E_CNT 131072
#define N_CNT 4096

typedef short bf16x8 __attribute__((ext_vector_type(8)));
typedef float f32x4 __attribute__((ext_vector_type(4)));

__device__ __forceinline__ ushort f2bf(float f) {
  union { float f; unsigned u; } v; v.f = f;
  unsigned r = v.u + 0x7FFFu + ((v.u >> 16) & 1u);
  return (ushort)(r >> 16);
}

// ---- prep: W1 combine+transpose | root1^T | deg | cvt_x ------------------
// [0,256):    wt1[r*64+o][i] = f2bf(sum_b att1[r,b]*basis1[b,i,o]), r<8
// [256,384):  root1^T -> wt1 rows 512..575
// [384,896):  degree histogram
// [896,9088): x fp32->bf16, 8 floats/thread (8192 blocks = 16.78M floats)
__global__ __launch_bounds__(256) void k_prep(const float* __restrict__ att1,
                                              const float* __restrict__ basis1,
                                              const float* __restrict__ root1,
                                              ushort* __restrict__ wt1,
                                              const int* __restrict__ dstp,
                                              int* __restrict__ deg,
                                              const float4* __restrict__ x,
                                              ushort* __restrict__ xbf) {
  __shared__ float sT[32 * 33];
  int bid = blockIdx.x, t = threadIdx.x;
  if (bid < 256) {
    int i0 = (bid >> 1) * 32, o0 = (bid & 1) * 32;
    int ol = t & 31, ir = t >> 5;      // ir = 0..7
    float a[8][4] = {};
    for (int b = 0; b < 30; b += 2) {  // unroll x2: 8 loads in flight
      float v0[4], v1[4];
#pragma unroll
      for (int k = 0; k < 4; ++k) {
        size_t ofs = (size_t)(i0 + ir + k * 8) * 64 + o0 + ol;
        v0[k] = basis1[(size_t)b * 262144 + ofs];
        v1[k] = basis1[(size_t)(b + 1) * 262144 + ofs];
      }
#pragma unroll
      for (int r = 0; r < 8; ++r) {
        float w0 = att1[r * 30 + b], w1 = att1[r * 30 + b + 1];
#pragma unroll
        for (int k = 0; k < 4; ++k) a[r][k] += w0 * v0[k] + w1 * v1[k];
      }
    }
    for (int r = 0; r < 8; ++r) {
#pragma unroll
      for (int k = 0; k < 4; ++k) sT[ol * 33 + ir + k * 8] = a[r][k];
      __syncthreads();
#pragma unroll
      for (int k = 0; k < 4; ++k) {
        int orow = ir + k * 8, icol = ol;
        wt1[(size_t)(r * 64 + o0 + orow) * 4096 + i0 + icol] = f2bf(sT[orow * 33 + icol]);
      }
      __syncthreads();
    }
  } else if (bid < 384) {
    int bb = bid - 256;                // 128 blocks: 32 i-rows each
    int i0 = bb * 32;
    int ol = t & 31, ir = t >> 5;
    for (int oh = 0; oh < 2; ++oh) {
      int o0 = oh * 32;
#pragma unroll
      for (int k = 0; k < 4; ++k)
        sT[ol * 33 + ir + k * 8] = root1[(size_t)(i0 + ir + k * 8) * 64 + o0 + ol];
      __syncthreads();
#pragma unroll
      for (int k = 0; k < 4; ++k) {
        int orow = ir + k * 8, icol = ol;
        wt1[(size_t)(512 + o0 + orow) * 4096 + i0 + icol] = f2bf(sT[orow * 33 + icol]);
      }
      __syncthreads();
    }
  } else if (bid < 896) {
    int e = (bid - 384) * 256 + t;
    atomicAdd(&deg[dstp[e]], 1);
  } else {
    int i = (bid - 896) * 256 + t;     // 8 floats / thread
    float4 v0 = x[i * 2], v1 = x[i * 2 + 1];
    ushort o[8];
    o[0] = f2bf(v0.x); o[1] = f2bf(v0.y); o[2] = f2bf(v0.z); o[3] = f2bf(v0.w);
    o[4] = f2bf(v1.x); o[5] = f2bf(v1.y); o[6] = f2bf(v1.z); o[7] = f2bf(v1.w);
    *(ulonglong2*)(xbf + (size_t)i * 8) = *(const ulonglong2*)o;
  }
}

// ---------------- exclusive scan over 4096 degrees (1 block) --------------
__global__ __launch_bounds__(1024) void k_scan(const int* __restrict__ deg,
                                               int* __restrict__ rowptr,
                                               int* __restrict__ cursor,
                                               float* __restrict__ dinv) {
  __shared__ int part[1024];
  int t = threadIdx.x;
  int base = t * 4;
  int d0 = deg[base], d1 = deg[base + 1], d2 = deg[base + 2], d3 = deg[base + 3];
  int s = d0 + d1 + d2 + d3;
  part[t] = s;
  __syncthreads();
  for (int off = 1; off < 1024; off <<= 1) {
    int v = part[t];
    int u = (t >= off) ? part[t - off] : 0;
    __syncthreads();
    part[t] = v + u;
    __syncthreads();
  }
  int incl = part[t];
  int excl = incl - s;
  int p0 = excl, p1 = excl + d0, p2 = p1 + d1, p3 = p2 + d2;
  rowptr[base] = p0; rowptr[base + 1] = p1; rowptr[base + 2] = p2; rowptr[base + 3] = p3;
  cursor[base] = p0; cursor[base + 1] = p1; cursor[base + 2] = p2; cursor[base + 3] = p3;
  dinv[base]     = 1.0f / fmaxf((float)d0, 1.0f);
  dinv[base + 1] = 1.0f / fmaxf((float)d1, 1.0f);
  dinv[base + 2] = 1.0f / fmaxf((float)d2, 1.0f);
  dinv[base + 3] = 1.0f / fmaxf((float)d3, 1.0f);
  if (t == 1023) rowptr[4096] = incl;
}

// ---------------- fused mid: CSR-fill | W2 combine -------------------------
__global__ __launch_bounds__(256) void k_mid(const int* __restrict__ srcp,
                                             const int* __restrict__ dstp,
                                             const int* __restrict__ et,
                                             int* __restrict__ cursor,
                                             int* __restrict__ spack,
                                             const float* __restrict__ att2,
                                             const float* __restrict__ basis2,
                                             const float* __restrict__ root2,
                                             float* __restrict__ w2e) {
  int bid = blockIdx.x, t = threadIdx.x;
  if (bid < 512) {
    int e = bid * 256 + t;
    int d = dstp[e];
    int pos = atomicAdd(&cursor[d], 1);
    spack[pos] = (srcp[e] << 3) | et[e];
  } else {
    int r = bid - 512;  // 0..8
    for (int q = t; q < 1024; q += 256) {
      float a = 0.f;
      if (r < 8) {
        for (int b = 0; b < 30; ++b) a += att2[r * 30 + b] * basis2[b * 1024 + q];
      } else {
        a = root2[q];
      }
      w2e[r * 1024 + q] = a;
    }
  }
}

// ---------------- GEMM v6: c1[4096][576] += xbf @ wt1^T -------------------
// R5's proven skeleton with ONE change: BK 64 -> 128 (2x MFMA per barrier,
// half the barriers; the measured invariant is ~1600 cyc per block-step).
// BM=128 BN=64 BK=128, SPLITK=4 (8 K-steps), 256 thr (2x2 waves, 64x32/wave,
// 4 ks of 32 per step -> 32 MFMA/wave/step). Single-buffer 48KB LDS ->
// 3 blocks/CU, grid 1152 (4.5/CU queued). Chunk-XOR swizzle both sides
// (16 chunks/row, XOR row&7 -> <=2-way banks). Atomic f32 epilogue (9.4M).
__global__ __launch_bounds__(256, 3) void k_gemm1(const ushort* __restrict__ xbf,
                                                  const ushort* __restrict__ wt1,
                                                  float* __restrict__ c1) {
  __shared__ __align__(16) ushort As[128 * 128];  // 32KB
  __shared__ __align__(16) ushort Bs[64 * 128];   // 16KB
  int bid = blockIdx.x;
  int swz = (bid & 7) * 144 + (bid >> 3);  // 1152 = 8*144, bijective
  int kp = swz / 288, rem = swz % 288;
  int bm = rem / 9, bn = rem % 9;
  int m0 = bm * 128, n0 = bn * 64, kbase = kp * 1024;
  int tid = threadIdx.x;
  int lane = tid & 63, wid = tid >> 6;
  int wm = wid >> 1, wn = wid & 1;

  f32x4 acc[4][2] = {};

  for (int tt = 0; tt < 8; ++tt) {
    int k0 = kbase + tt * 128;
    // A: 128 rows x 128 k bf16 = 32KB = 8 iters
#pragma unroll
    for (int it = 0; it < 8; ++it) {
      int flat = it * 256 + tid;
      int row = flat >> 4, gg = flat & 15;
      int gcol = k0 + ((gg ^ (row & 7)) << 3);  // pre-swizzled global source
      const ushort* g = xbf + (size_t)(m0 + row) * 4096 + gcol;
      ushort* l = &As[(it * 256 + wid * 64) * 8];  // linear LDS dest
      __builtin_amdgcn_global_load_lds((const __attribute__((address_space(1))) void*)g,
                                       (__attribute__((address_space(3))) void*)l, 16, 0, 0);
    }
    // B: 64 rows x 128 k = 16KB = 4 iters
#pragma unroll
    for (int it = 0; it < 4; ++it) {
      int flat = it * 256 + tid;
      int row = flat >> 4, gg = flat & 15;
      int gcol = k0 + ((gg ^ (row & 7)) << 3);
      const ushort* g = wt1 + (size_t)(n0 + row) * 4096 + gcol;
      ushort* l = &Bs[(it * 256 + wid * 64) * 8];
      __builtin_amdgcn_global_load_lds((const __attribute__((address_space(1))) void*)g,
                                       (__attribute__((address_space(3))) void*)l, 16, 0, 0);
    }
    __syncthreads();  // vmcnt(0) drain: all waves' stage landed
    int q = lane >> 4, sw = lane & 7, r16 = lane & 15;
#pragma unroll
    for (int ks = 0; ks < 4; ++ks) {
      int co = ((ks * 4 + q) ^ sw) << 3;
      bf16x8 b0 = *(const bf16x8*)&Bs[(wn * 32 + 0 * 16 + r16) * 128 + co];
      bf16x8 b1 = *(const bf16x8*)&Bs[(wn * 32 + 1 * 16 + r16) * 128 + co];
      bf16x8 a0 = *(const bf16x8*)&As[(wm * 64 + 0 * 16 + r16) * 128 + co];
      bf16x8 a1 = *(const bf16x8*)&As[(wm * 64 + 1 * 16 + r16) * 128 + co];
      bf16x8 a2 = *(const bf16x8*)&As[(wm * 64 + 2 * 16 + r16) * 128 + co];
      bf16x8 a3 = *(const bf16x8*)&As[(wm * 64 + 3 * 16 + r16) * 128 + co];
      __builtin_amdgcn_s_setprio(1);
      acc[0][0] = __builtin_amdgcn_mfma_f32_16x16x32_bf16(a0, b0, acc[0][0], 0, 0, 0);
      acc[0][1] = __builtin_amdgcn_mfma_f32_16x16x32_bf16(a0, b1, acc[0][1], 0, 0, 0);
      acc[1][0] = __builtin_amdgcn_mfma_f32_16x16x32_bf16(a1, b0, acc[1][0], 0, 0, 0);
      acc[1][1] = __builtin_amdgcn_mfma_f32_16x16x32_bf16(a1, b1, acc[1][1], 0, 0, 0);
      acc[2][0] = __builtin_amdgcn_mfma_f32_16x16x32_bf16(a2, b0, acc[2][0], 0, 0, 0);
      acc[2][1] = __builtin_amdgcn_mfma_f32_16x16x32_bf16(a2, b1, acc[2][1], 0, 0, 0);
      acc[3][0] = __builtin_amdgcn_mfma_f32_16x16x32_bf16(a3, b0, acc[3][0], 0, 0, 0);
      acc[3][1] = __builtin_amdgcn_mfma_f32_16x16x32_bf16(a3, b1, acc[3][1], 0, 0, 0);
      __builtin_amdgcn_s_setprio(0);
    }
    __syncthreads();  // LDS free for next stage
  }

  int cf = lane & 15, rf4 = (lane >> 4) * 4;
#pragma unroll
  for (int mi = 0; mi < 4; ++mi)
#pragma unroll
    for (int ni = 0; ni < 2; ++ni) {
      int gcol = n0 + wn * 32 + ni * 16 + cf;
#pragma unroll
      for (int j = 0; j < 4; ++j) {
        int grow = m0 + wm * 64 + mi * 16 + rf4 + j;
        atomicAdd(&c1[(size_t)grow * 576 + gcol], acc[mi][ni][j]);
      }
    }
}

// -------- fused layer-1 aggregate + relu + layer-2 transform (4 nodes/blk) -
__global__ __launch_bounds__(256) void k_agg1h2(const float* __restrict__ c1,
                                                const int* __restrict__ rowptr,
                                                const int* __restrict__ spack,
                                                const float* __restrict__ dinv,
                                                const float* __restrict__ bias1,
                                                const float* __restrict__ w2e,
                                                float* __restrict__ h2c) {
  __shared__ float sh[4][64];
  int g = threadIdx.x >> 6, t = threadIdx.x & 63;
  int n = blockIdx.x * 4 + g;
  int s0 = rowptr[n], s1 = rowptr[n + 1];
  float acc = 0.f;
  int e = s0;
  for (; e + 3 < s1; e += 4) {
    int p0 = spack[e], p1 = spack[e + 1], p2 = spack[e + 2], p3 = spack[e + 3];
    float v0 = c1[(size_t)(p0 >> 3) * 576 + (p0 & 7) * 64 + t];
    float v1 = c1[(size_t)(p1 >> 3) * 576 + (p1 & 7) * 64 + t];
    float v2 = c1[(size_t)(p2 >> 3) * 576 + (p2 & 7) * 64 + t];
    float v3 = c1[(size_t)(p3 >> 3) * 576 + (p3 & 7) * 64 + t];
    acc += (v0 + v1) + (v2 + v3);
  }
  for (; e < s1; ++e) {
    int p = spack[e];
    acc += c1[(size_t)(p >> 3) * 576 + (p & 7) * 64 + t];
  }
  float v = acc * dinv[n] + c1[(size_t)n * 576 + 512 + t] + bias1[t];
  sh[g][t] = fmaxf(v, 0.f);
  __syncthreads();
  float* o = h2c + (size_t)n * 144;
  for (int rc = t; rc < 144; rc += 64) {
    int r9 = rc >> 4, c = rc & 15;
    const float* w = w2e + r9 * 1024 + c;
    float a = 0.f;
#pragma unroll
    for (int hh = 0; hh < 64; ++hh) a += sh[g][hh] * w[hh * 16];
    o[rc] = a;
  }
}

// ---------------- layer-2 aggregate + root + bias + log_softmax -----------
__global__ __launch_bounds__(64) void k_agg2(const float* __restrict__ h2c,
                                             const int* __restrict__ rowptr,
                                             const int* __restrict__ spack,
                                             const float* __restrict__ dinv,
                                             const float* __restrict__ bias2,
                                             float* __restrict__ out) {
  __shared__ float red[64];
  int n = blockIdx.x, t = threadIdx.x;
  int c = t & 15, q = t >> 4;
  int s0 = rowptr[n], s1 = rowptr[n + 1];
  float acc = 0.f;
  for (int e = s0 + q; e < s1; e += 4) {
    int p = spack[e];
    acc += h2c[(size_t)(p >> 3) * 144 + (p & 7) * 16 + c];
  }
  red[t] = acc;
  __syncthreads();
  if (t < 16) {
    float sum = red[c] + red[16 + c] + red[32 + c] + red[48 + c];
    float v = sum * dinv[n] + h2c[(size_t)n * 144 + 128 + c] + bias2[c];
    float m = v;
#pragma unroll
    for (int off = 1; off < 16; off <<= 1) m = fmaxf(m, __shfl_xor(m, off, 64));
    float ex = expf(v - m);
    float s = ex;
#pragma unroll
    for (int off = 1; off < 16; off <<= 1) s += __shfl_xor(s, off, 64);
    out[n * 16 + c] = v - m - logf(s);
  }
}

extern "C" void kernel_launch(void* const* d_in, const int* in_sizes, int n_in,
                              void* d_out, int out_size, void* d_ws, size_t ws_size,
                              hipStream_t stream) {
  const float* x      = (const float*)d_in[0];
  const int*   ei     = (const int*)d_in[1];
  const int*   et     = (const int*)d_in[2];
  const float* basis1 = (const float*)d_in[3];
  const float* att1   = (const float*)d_in[4];
  const float* root1  = (const float*)d_in[5];
  const float* bias1  = (const float*)d_in[6];
  const float* basis2 = (const float*)d_in[7];
  const float* att2   = (const float*)d_in[8];
  const float* root2  = (const float*)d_in[9];
  const float* bias2  = (const float*)d_in[10];
  float* out = (float*)d_out;

  char* ws = (char*)d_ws;
  size_t off = 0;
  auto alloc = [&](size_t bytes) {
    void* p = ws + off;
    off = (off + bytes + 255) & ~(size_t)255;
    return p;
  };
  ushort* xbf  = (ushort*)alloc((size_t)N_CNT * N_CNT * 2);
  ushort* wt1  = (ushort*)alloc((size_t)576 * 4096 * 2);
  float*  c1   = (float*)alloc((size_t)N_CNT * 576 * 4);
  float*  w2e  = (float*)alloc((size_t)9 * 64 * 16 * 4);
  float*  h2c  = (float*)alloc((size_t)N_CNT * 144 * 4);
  int*    deg    = (int*)alloc(4096 * 4);
  float*  dinv   = (float*)alloc(4096 * 4);
  int*    rowptr = (int*)alloc(4097 * 4);
  int*    cursor = (int*)alloc(4096 * 4);
  int*    spack  = (int*)alloc((size_t)E_CNT * 4);

  const int* srcp = ei;
  const int* dstp = ei + E_CNT;

  hipMemsetAsync(deg, 0, 4096 * 4, stream);
  hipMemsetAsync(c1, 0, (size_t)N_CNT * 576 * 4, stream);
  k_prep<<<9088, 256, 0, stream>>>(att1, basis1, root1, wt1, dstp, deg,
                                   (const float4*)x, xbf);
  k_scan<<<1, 1024, 0, stream>>>(deg, rowptr, cursor, dinv);
  k_mid<<<521, 256, 0, stream>>>(srcp, dstp, et, cursor, spack,
                                 att2, basis2, root2, w2e);
  k_gemm1<<<1152, 256, 0, stream>>>(xbf, wt1, c1);
  k_agg1h2<<<1024, 256, 0, stream>>>(c1, rowptr, spack, dinv, bias1, w2e, h2c);
  k_agg2<<<4096, 64, 0, stream>>>(h2c, rowptr, spack, dinv, bias2, out);
}